// Round 1
// baseline (146.576 us; speedup 1.0000x reference)
//
#include <hip/hip_runtime.h>
#include <stdint.h>

typedef float  floatx4 __attribute__((ext_vector_type(4)));
typedef short  short8  __attribute__((ext_vector_type(8)));
typedef float  f4v     __attribute__((ext_vector_type(4)));
typedef unsigned int uint32;

#define GS_EPS 1e-10f
#define W1T_STRIDE 264   // 256 + 8 bf16 pad: keeps ds_read_b128 16B-aligned, 2-way-max bank aliasing

__device__ __forceinline__ unsigned short f2bf(float x) {
  // round-to-nearest-even fp32 -> bf16
  uint32 u = __float_as_uint(x);
  u += 0x7FFFu + ((u >> 16) & 1u);
  return (unsigned short)(u >> 16);
}

// ---- prep: node_embed fp32 -> bf16 table in workspace ----
__global__ void conv_nodes_kernel(const float* __restrict__ src,
                                  unsigned short* __restrict__ dst, int n4) {
  int i = blockIdx.x * 256 + threadIdx.x;
  if (i < n4) {
    f4v v = *(const f4v*)(src + (size_t)i * 4);
    uint32 lo = (uint32)f2bf(v[0]) | ((uint32)f2bf(v[1]) << 16);
    uint32 hi = (uint32)f2bf(v[2]) | ((uint32)f2bf(v[3]) << 16);
    uint32* d = (uint32*)(dst + (size_t)i * 4);
    d[0] = lo;
    d[1] = hi;
  }
}

// ---- main fused kernel ----
// Block = 256 threads = 4 waves. Block covers 256 edges; each wave 64 edges
// as 4 M-tiles of mfma_f32_16x16x32_bf16 (M=16 edges, N=64 hidden in 4 tiles,
// K=256 features in 8 steps).
template <bool BF16N>
__global__ __launch_bounds__(256, 4) void edge_mlp_kernel(
    const float* __restrict__ node_f32,
    const unsigned short* __restrict__ node_bf16,
    const int* __restrict__ ei,
    const float* __restrict__ u1, const float* __restrict__ u2,
    const float* __restrict__ W1, const float* __restrict__ b1,
    const float* __restrict__ W2, const float* __restrict__ b2,
    float* __restrict__ out, int num_edges) {
  __shared__ unsigned short w1t[64 * W1T_STRIDE];  // W1^T bf16, [n][k] stride 264
  __shared__ float sb1[64];
  __shared__ float sw2[64];
  __shared__ int s_idx64;

  const int tid = threadIdx.x;

  // ---- int64-vs-int32 edge_index detection (wave/block-uniform result) ----
  // If edge_index is int64 little-endian with values < 2^31, every odd int32
  // word is 0. With int32 data those words are random node ids (~never all 0).
  if (tid == 0) s_idx64 = 1;
  __syncthreads();
  if (2 * tid + 1 < 2 * num_edges) {
    if (ei[2 * tid + 1] != 0) s_idx64 = 0;  // benign race: all writers store 0
  }

  // ---- stage W1^T into LDS as bf16 (each block reads W1 once, 64 KB, L2-hot) ----
#pragma unroll 4
  for (int it = 0; it < 32; ++it) {
    int pid = it * 256 + tid;   // 0..8191 : pairs of k for one n
    int n = pid & 63;
    int k2 = pid >> 6;          // k = 2*k2, 2*k2+1
    float wlo = W1[(2 * k2) * 64 + n];
    float whi = W1[(2 * k2 + 1) * 64 + n];
    uint32 packed = (uint32)f2bf(wlo) | ((uint32)f2bf(whi) << 16);
    *(uint32*)&w1t[n * W1T_STRIDE + 2 * k2] = packed;
  }
  if (tid < 64) {
    sb1[tid] = b1[tid];
    sw2[tid] = W2[tid];
  }
  __syncthreads();
  const bool idx64 = (s_idx64 != 0);

  const int lane = tid & 63;
  const int wave = tid >> 6;
  const int quad = lane >> 4;
  const int l16 = lane & 15;
  const int wavebase = blockIdx.x * 256 + wave * 64;

  // node indices for this wave's 4 M-tiles (lane l16 = row m within tile)
  int nr[4], nc[4];
#pragma unroll
  for (int mt = 0; mt < 4; ++mt) {
    int e = wavebase + mt * 16 + l16;
    if (e > num_edges - 1) e = num_edges - 1;  // clamp; OOB rows never stored
    if (idx64) {
      nr[mt] = ei[2 * e];
      nc[mt] = ei[2 * (num_edges + e)];
    } else {
      nr[mt] = ei[e];
      nc[mt] = ei[num_edges + e];
    }
  }

  floatx4 acc[4][4];  // [mt][nn]
#pragma unroll
  for (int mt = 0; mt < 4; ++mt)
#pragma unroll
    for (int nn = 0; nn < 4; ++nn) {
      floatx4 z = {0.f, 0.f, 0.f, 0.f};
      acc[mt][nn] = z;
    }

#pragma unroll
  for (int kk = 0; kk < 8; ++kk) {
    // B fragments: B[k][n], n = l16, k = kk*32 + quad*8 + j  -> one ds_read_b128
    short8 bfrag[4];
#pragma unroll
    for (int nn = 0; nn < 4; ++nn) {
      bfrag[nn] = *(const short8*)&w1t[(nn * 16 + l16) * W1T_STRIDE + kk * 32 + quad * 8];
    }
    // A fragments: feature[kk*32 + quad*8 + j] of edge m=l16
    // kk<4 -> row node (features 0..127), kk>=4 -> col node (128..255)
    const int off = (kk & 3) * 32 + quad * 8;
    short8 af[4];
#pragma unroll
    for (int mt = 0; mt < 4; ++mt) {
      int node = (kk < 4) ? nr[mt] : nc[mt];
      if (BF16N) {
        af[mt] = *(const short8*)(node_bf16 + (size_t)node * 128 + off);
      } else {
        const float* p = node_f32 + (size_t)node * 128 + off;
        f4v v0 = *(const f4v*)p;
        f4v v1 = *(const f4v*)(p + 4);
        short8 t;
        t[0] = (short)f2bf(v0[0]); t[1] = (short)f2bf(v0[1]);
        t[2] = (short)f2bf(v0[2]); t[3] = (short)f2bf(v0[3]);
        t[4] = (short)f2bf(v1[0]); t[5] = (short)f2bf(v1[1]);
        t[6] = (short)f2bf(v1[2]); t[7] = (short)f2bf(v1[3]);
        af[mt] = t;
      }
    }
#pragma unroll
    for (int mt = 0; mt < 4; ++mt)
#pragma unroll
      for (int nn = 0; nn < 4; ++nn)
        acc[mt][nn] = __builtin_amdgcn_mfma_f32_16x16x32_bf16(af[mt], bfrag[nn],
                                                              acc[mt][nn], 0, 0, 0);
  }

  // ---- epilogue: bias+relu, dot with W2, reduce over n, gumbel-sigmoid ----
  // C/D layout: col(n within tile) = l16, row(m within tile) = quad*4 + reg
  float b1v[4], w2v[4];
#pragma unroll
  for (int nn = 0; nn < 4; ++nn) {
    int n = nn * 16 + l16;
    b1v[nn] = sb1[n];
    w2v[nn] = sw2[n];
  }
  const float bias2 = b2[0];

#pragma unroll
  for (int mt = 0; mt < 4; ++mt) {
    float p0 = 0.f, p1 = 0.f, p2 = 0.f, p3 = 0.f;
#pragma unroll
    for (int nn = 0; nn < 4; ++nn) {
      floatx4 a = acc[mt][nn];
      float bb = b1v[nn], ww = w2v[nn];
      p0 += fmaxf(a[0] + bb, 0.f) * ww;
      p1 += fmaxf(a[1] + bb, 0.f) * ww;
      p2 += fmaxf(a[2] + bb, 0.f) * ww;
      p3 += fmaxf(a[3] + bb, 0.f) * ww;
    }
    // sum over the 16 lanes of this quad (they hold different n)
#pragma unroll
    for (int s = 1; s < 16; s <<= 1) {
      p0 += __shfl_xor(p0, s, 64);
      p1 += __shfl_xor(p1, s, 64);
      p2 += __shfl_xor(p2, s, 64);
      p3 += __shfl_xor(p3, s, 64);
    }
    int t = l16;
    if (t < 4) {
      float logit = (t == 0) ? p0 : (t == 1) ? p1 : (t == 2) ? p2 : p3;
      logit += bias2;
      int e = wavebase + mt * 16 + quad * 4 + t;
      if (e < num_edges) {
        float a1 = fminf(fmaxf(u1[e], GS_EPS), 1.0f);
        float a2 = fminf(fmaxf(u2[e], GS_EPS), 1.0f);
        float g1 = -__logf(-__logf(a1));
        float g2 = -__logf(-__logf(a2));
        float x = logit + g1 - g2;   // TEMP = 1.0
        out[e] = 1.f / (1.f + __expf(-x));
      }
    }
  }
}

extern "C" void kernel_launch(void* const* d_in, const int* in_sizes, int n_in,
                              void* d_out, int out_size, void* d_ws, size_t ws_size,
                              hipStream_t stream) {
  const float* node_embed = (const float*)d_in[0];
  const int* ei = (const int*)d_in[1];
  const float* u1 = (const float*)d_in[2];
  const float* u2 = (const float*)d_in[3];
  const float* W1 = (const float*)d_in[4];
  const float* b1 = (const float*)d_in[5];
  const float* W2 = (const float*)d_in[6];
  const float* b2 = (const float*)d_in[7];
  float* out = (float*)d_out;

  const int num_edges = in_sizes[2];        // u1 length — dtype-independent
  const int num_nodes = in_sizes[0] / 128;  // embed_dim = 128
  const int nblocks = (num_edges + 255) / 256;

  const size_t node_tbl_bytes = (size_t)num_nodes * 128 * sizeof(unsigned short);
  if (ws_size >= node_tbl_bytes) {
    unsigned short* node_bf16 = (unsigned short*)d_ws;
    int n4 = (num_nodes * 128) / 4;
    int cgrid = (n4 + 255) / 256;
    conv_nodes_kernel<<<cgrid, 256, 0, stream>>>(node_embed, node_bf16, n4);
    edge_mlp_kernel<true><<<nblocks, 256, 0, stream>>>(
        node_embed, node_bf16, ei, u1, u2, W1, b1, W2, b2, out, num_edges);
  } else {
    edge_mlp_kernel<false><<<nblocks, 256, 0, stream>>>(
        node_embed, nullptr, ei, u1, u2, W1, b1, W2, b2, out, num_edges);
  }
}

// Round 2
// 136.149 us; speedup vs baseline: 1.0766x; 1.0766x over previous
//
#include <hip/hip_runtime.h>
#include <stdint.h>

typedef float  floatx4 __attribute__((ext_vector_type(4)));
typedef short  short8  __attribute__((ext_vector_type(8)));
typedef float  f4v     __attribute__((ext_vector_type(4)));
typedef unsigned int uint32;

#define GS_EPS 1e-10f

__device__ __forceinline__ unsigned short f2bf(float x) {
  uint32 u = __float_as_uint(x);
  u += 0x7FFFu + ((u >> 16) & 1u);
  return (unsigned short)(u >> 16);
}

// ---- prep 1: node_embed fp32 -> bf16 table ----
__global__ void conv_nodes_kernel(const float* __restrict__ src,
                                  unsigned short* __restrict__ dst, int n4) {
  int i = blockIdx.x * 256 + threadIdx.x;
  if (i < n4) {
    f4v v = *(const f4v*)(src + (size_t)i * 4);
    uint32 lo = (uint32)f2bf(v[0]) | ((uint32)f2bf(v[1]) << 16);
    uint32 hi = (uint32)f2bf(v[2]) | ((uint32)f2bf(v[3]) << 16);
    uint32* d = (uint32*)(dst + (size_t)i * 4);
    d[0] = lo;
    d[1] = hi;
  }
}

// ---- prep 2: W1 fp32 [256][64] -> bf16 blocked [chunk=k/8][n][k%8] ----
__global__ void conv_w1_kernel(const float* __restrict__ W1,
                               unsigned short* __restrict__ w1blk) {
  int i = blockIdx.x * 256 + threadIdx.x;  // 0..2047 = chunk*64 + n
  int chunk = i >> 6;
  int n = i & 63;
  uint32 d[4];
#pragma unroll
  for (int j = 0; j < 4; ++j) {
    unsigned short lo = f2bf(W1[(chunk * 8 + 2 * j) * 64 + n]);
    unsigned short hi = f2bf(W1[(chunk * 8 + 2 * j + 1) * 64 + n]);
    d[j] = (uint32)lo | ((uint32)hi << 16);
  }
  *(uint32*)&w1blk[(size_t)i * 8 + 0] = d[0];
  *(uint32*)&w1blk[(size_t)i * 8 + 2] = d[1];
  *(uint32*)&w1blk[(size_t)i * 8 + 4] = d[2];
  *(uint32*)&w1blk[(size_t)i * 8 + 6] = d[3];
}

// ---- main fused kernel ----
// Block = 512 threads = 8 waves; each wave owns 32 edges (2 M-tiles of
// mfma_f32_16x16x32_bf16), block = 256 edges. W1^T bf16 in LDS, blocked
// chunk-major (conflict-free b128 reads AND writes).
#define REDS 272  // 16*17 floats per-wave reduction buffer
__global__ __launch_bounds__(512, 6) void edge_mlp_kernel(
    const unsigned short* __restrict__ node_bf16,
    const unsigned short* __restrict__ w1g,
    const int* __restrict__ ei,
    const float* __restrict__ u1, const float* __restrict__ u2,
    const float* __restrict__ b1, const float* __restrict__ W2,
    const float* __restrict__ b2,
    float* __restrict__ out, int num_edges) {
  __shared__ __align__(16) unsigned short w1blk[32 * 64 * 8];  // 32 KB
  __shared__ float red[8 * REDS];                              // 8.5 KB
  __shared__ float sb1[64];
  __shared__ float sw2[64];
  __shared__ int s_idx64;

  const int tid = threadIdx.x;
  const int wave = tid >> 6;
  const int lane = tid & 63;
  const int q = lane >> 4;
  const int l16 = lane & 15;

  // int64-vs-int32 edge_index detection (block-uniform result)
  if (tid == 0) s_idx64 = 1;
  __syncthreads();
  if (2 * tid + 1 < 2 * num_edges) {
    if (ei[2 * tid + 1] != 0) s_idx64 = 0;
  }

  // stage W1 (pre-converted bf16, blocked): 2048 chunks of 16B, coalesced
  // global b128 reads, conflict-free ds_write_b128 (consecutive lanes ->
  // consecutive 16B).
#pragma unroll
  for (int it = 0; it < 4; ++it) {
    int idx = it * 512 + tid;
    short8 v = *(const short8*)(w1g + (size_t)idx * 8);
    *(short8*)&w1blk[(size_t)idx * 8] = v;
  }
  if (tid < 64) {
    sb1[tid] = b1[tid];
    sw2[tid] = W2[tid];
  }
  __syncthreads();
  const bool idx64 = (s_idx64 != 0);

  const int wavebase = blockIdx.x * 256 + wave * 32;

  // node indices for this wave's 2 M-tiles (lane l16 = row m within tile)
  int nr[2], nc[2];
#pragma unroll
  for (int mt = 0; mt < 2; ++mt) {
    int e = wavebase + mt * 16 + l16;
    if (e > num_edges - 1) e = num_edges - 1;
    if (idx64) {
      nr[mt] = ei[2 * e];
      nc[mt] = ei[2 * (num_edges + e)];
    } else {
      nr[mt] = ei[e];
      nc[mt] = ei[num_edges + e];
    }
  }

  floatx4 acc[2][4];
#pragma unroll
  for (int mt = 0; mt < 2; ++mt)
#pragma unroll
    for (int nn = 0; nn < 4; ++nn) {
      floatx4 z = {0.f, 0.f, 0.f, 0.f};
      acc[mt][nn] = z;
    }

  // K loop: kk 0..3 -> row node features, 4..7 -> col node features.
  // A-fragment double buffer: prefetch kk+1 while MFMA on kk.
  short8 acur[2], anxt[2];
#pragma unroll
  for (int mt = 0; mt < 2; ++mt)
    acur[mt] = *(const short8*)(node_bf16 + (size_t)nr[mt] * 128 + q * 8);

#pragma unroll
  for (int kk = 0; kk < 8; ++kk) {
    if (kk < 7) {
      int kn = kk + 1;
      int off = (kn & 3) * 32 + q * 8;
#pragma unroll
      for (int mt = 0; mt < 2; ++mt) {
        int node = (kn < 4) ? nr[mt] : nc[mt];
        anxt[mt] = *(const short8*)(node_bf16 + (size_t)node * 128 + off);
      }
    }
    short8 bf[4];
#pragma unroll
    for (int nn = 0; nn < 4; ++nn)
      bf[nn] = *(const short8*)&w1blk[(size_t)((kk * 4 + q) * 64 + nn * 16 + l16) * 8];
#pragma unroll
    for (int mt = 0; mt < 2; ++mt)
#pragma unroll
      for (int nn = 0; nn < 4; ++nn)
        acc[mt][nn] = __builtin_amdgcn_mfma_f32_16x16x32_bf16(acur[mt], bf[nn],
                                                              acc[mt][nn], 0, 0, 0);
    acur[0] = anxt[0];
    acur[1] = anxt[1];
  }

  // ---- epilogue ----
  // C/D layout: col(n within tile) = l16, row(m within tile) = q*4 + reg.
  float b1v[4], w2v[4];
#pragma unroll
  for (int nn = 0; nn < 4; ++nn) {
    int n = nn * 16 + l16;
    b1v[nn] = sb1[n];
    w2v[nn] = sw2[n];
  }
  const float bias2 = b2[0];

  float* rw = &red[wave * REDS];
  float logitA = 0.f, logitB = 0.f;
#pragma unroll
  for (int mt = 0; mt < 2; ++mt) {
    float p[4];
#pragma unroll
    for (int r = 0; r < 4; ++r) p[r] = 0.f;
#pragma unroll
    for (int nn = 0; nn < 4; ++nn) {
      floatx4 a = acc[mt][nn];
      float bb = b1v[nn], ww = w2v[nn];
      p[0] += fmaxf(a[0] + bb, 0.f) * ww;
      p[1] += fmaxf(a[1] + bb, 0.f) * ww;
      p[2] += fmaxf(a[2] + bb, 0.f) * ww;
      p[3] += fmaxf(a[3] + bb, 0.f) * ww;
    }
    // LDS transpose-reduce within the wave (lockstep; in-order LDS pipe).
    // write: partial for edge m=q*4+r, partial-index l16
#pragma unroll
    for (int r = 0; r < 4; ++r) rw[(q * 4 + r) * 17 + l16] = p[r];
    // read transposed: lane (q,l16) sums quarter q of edge l16
    float s = rw[l16 * 17 + q * 4 + 0] + rw[l16 * 17 + q * 4 + 1] +
              rw[l16 * 17 + q * 4 + 2] + rw[l16 * 17 + q * 4 + 3];
    s += __shfl_xor(s, 16, 64);
    s += __shfl_xor(s, 32, 64);  // all lanes: total for edge l16 of this mt
    if (mt == 0) logitA = s; else logitB = s;
  }

  // lanes 0..31 store edges wavebase+lane (coalesced): lane<16 -> mt0 edge l16,
  // lane 16..31 -> mt1 edge l16.
  if (lane < 32) {
    float logit = ((lane < 16) ? logitA : logitB) + bias2;
    int e = wavebase + lane;
    if (e < num_edges) {
      float a1 = fminf(fmaxf(u1[e], GS_EPS), 1.0f);
      float a2 = fminf(fmaxf(u2[e], GS_EPS), 1.0f);
      float g1 = -__logf(-__logf(a1));
      float g2 = -__logf(-__logf(a2));
      float x = logit + g1 - g2;  // TEMP = 1.0
      out[e] = 1.f / (1.f + __expf(-x));
    }
  }
}

extern "C" void kernel_launch(void* const* d_in, const int* in_sizes, int n_in,
                              void* d_out, int out_size, void* d_ws, size_t ws_size,
                              hipStream_t stream) {
  const float* node_embed = (const float*)d_in[0];
  const int* ei = (const int*)d_in[1];
  const float* u1 = (const float*)d_in[2];
  const float* u2 = (const float*)d_in[3];
  const float* W1 = (const float*)d_in[4];
  const float* b1 = (const float*)d_in[5];
  const float* W2 = (const float*)d_in[6];
  const float* b2 = (const float*)d_in[7];
  float* out = (float*)d_out;

  const int num_edges = in_sizes[2];        // u1 length
  const int num_nodes = in_sizes[0] / 128;  // embed_dim = 128

  unsigned short* node_bf16 = (unsigned short*)d_ws;
  const size_t node_tbl_bytes = (size_t)num_nodes * 128 * sizeof(unsigned short);
  unsigned short* w1blk = (unsigned short*)((char*)d_ws + ((node_tbl_bytes + 15) & ~(size_t)15));

  int n4 = (num_nodes * 128) / 4;
  conv_nodes_kernel<<<(n4 + 255) / 256, 256, 0, stream>>>(node_embed, node_bf16, n4);
  conv_w1_kernel<<<8, 256, 0, stream>>>(W1, w1blk);

  const int nblocks = (num_edges + 255) / 256;
  edge_mlp_kernel<<<nblocks, 512, 0, stream>>>(
      node_bf16, w1blk, ei, u1, u2, b1, W2, b2, out, num_edges);
}

// Round 3
// 135.690 us; speedup vs baseline: 1.0802x; 1.0034x over previous
//
#include <hip/hip_runtime.h>
#include <stdint.h>

typedef float  floatx4 __attribute__((ext_vector_type(4)));
typedef short  short8  __attribute__((ext_vector_type(8)));
typedef float  f4v     __attribute__((ext_vector_type(4)));
typedef unsigned int uint32;

#define GS_EPS 1e-10f

__device__ __forceinline__ unsigned short f2bf(float x) {
  uint32 u = __float_as_uint(x);
  u += 0x7FFFu + ((u >> 16) & 1u);
  return (unsigned short)(u >> 16);
}

// ---- prep 1: node_embed fp32 -> bf16 table (8 floats / thread) ----
__global__ void conv_nodes_kernel(const float* __restrict__ src,
                                  unsigned short* __restrict__ dst, int n8) {
  int i = blockIdx.x * 256 + threadIdx.x;
  if (i < n8) {
    f4v v0 = *(const f4v*)(src + (size_t)i * 8);
    f4v v1 = *(const f4v*)(src + (size_t)i * 8 + 4);
    short8 t;
    t[0] = (short)f2bf(v0[0]); t[1] = (short)f2bf(v0[1]);
    t[2] = (short)f2bf(v0[2]); t[3] = (short)f2bf(v0[3]);
    t[4] = (short)f2bf(v1[0]); t[5] = (short)f2bf(v1[1]);
    t[6] = (short)f2bf(v1[2]); t[7] = (short)f2bf(v1[3]);
    *(short8*)(dst + (size_t)i * 8) = t;
  }
}

// ---- prep 2: W1 fp32 [256][64] -> bf16 blocked [chunk=k/8][n][k%8] ----
__global__ void conv_w1_kernel(const float* __restrict__ W1,
                               unsigned short* __restrict__ w1blk) {
  int i = blockIdx.x * 256 + threadIdx.x;  // 0..2047 = chunk*64 + n
  int chunk = i >> 6;
  int n = i & 63;
  uint32 d[4];
#pragma unroll
  for (int j = 0; j < 4; ++j) {
    unsigned short lo = f2bf(W1[(chunk * 8 + 2 * j) * 64 + n]);
    unsigned short hi = f2bf(W1[(chunk * 8 + 2 * j + 1) * 64 + n]);
    d[j] = (uint32)lo | ((uint32)hi << 16);
  }
  *(uint32*)&w1blk[(size_t)i * 8 + 0] = d[0];
  *(uint32*)&w1blk[(size_t)i * 8 + 2] = d[1];
  *(uint32*)&w1blk[(size_t)i * 8 + 4] = d[2];
  *(uint32*)&w1blk[(size_t)i * 8 + 6] = d[3];
}

// ---- main fused kernel ----
// Block = 512 threads = 8 waves; each wave owns 16 edges (one M-tile of
// mfma_f32_16x16x32_bf16), block = 128 edges. LDS = W1 bf16 only (32 KB)
// -> 4 blocks/CU. All 8 A-fragments gathered up-front (8 loads in flight).
__global__ __launch_bounds__(512, 8) void edge_mlp_kernel(
    const unsigned short* __restrict__ node_bf16,
    const unsigned short* __restrict__ w1g,
    const int* __restrict__ ei,
    const float* __restrict__ u1, const float* __restrict__ u2,
    const float* __restrict__ b1, const float* __restrict__ W2,
    const float* __restrict__ b2,
    float* __restrict__ out, int num_edges) {
  __shared__ __align__(16) unsigned short w1blk[32 * 64 * 8];  // 32 KB exactly

  const int tid = threadIdx.x;
  const int wave = tid >> 6;
  const int lane = tid & 63;
  const int q = lane >> 4;
  const int l16 = lane & 15;
  const int wavebase = blockIdx.x * 128 + wave * 16;

  // stage W1 (pre-converted bf16, blocked): coalesced b128 global reads,
  // conflict-free ds_write_b128.
#pragma unroll
  for (int it = 0; it < 4; ++it) {
    int idx = it * 512 + tid;
    short8 v = *(const short8*)(w1g + (size_t)idx * 8);
    *(short8*)&w1blk[(size_t)idx * 8] = v;
  }

  // int64-vs-int32 edge_index detection, per-wave uniform via ballot:
  // int64 little-endian (values < 2^31) => every odd int32 word is 0.
  int el = wavebase + lane;
  if (el > num_edges - 1) el = num_edges - 1;
  unsigned long long oddmask = __ballot(ei[2 * el + 1] != 0);
  const bool idx64 = (oddmask == 0ULL);

  // this wave's 16 edges: lane l16 = row m within the M-tile
  int e = wavebase + l16;
  if (e > num_edges - 1) e = num_edges - 1;  // clamp; OOB rows never stored
  int nr, nc;
  if (idx64) {
    nr = ei[2 * e];
    nc = ei[2 * (num_edges + e)];
  } else {
    nr = ei[e];
    nc = ei[num_edges + e];
  }

  // gather ALL 8 A-fragments up-front: kk<4 -> row node feats 0..127,
  // kk>=4 -> col node feats 128..255; k = kk*32 + q*8 + j.
  short8 af[8];
  {
    const unsigned short* pr = node_bf16 + (size_t)nr * 128 + q * 8;
    const unsigned short* pc = node_bf16 + (size_t)nc * 128 + q * 8;
#pragma unroll
    for (int kk = 0; kk < 4; ++kk) af[kk] = *(const short8*)(pr + kk * 32);
#pragma unroll
    for (int kk = 0; kk < 4; ++kk) af[4 + kk] = *(const short8*)(pc + kk * 32);
  }

  __syncthreads();

  floatx4 acc[4];
#pragma unroll
  for (int nn = 0; nn < 4; ++nn) {
    floatx4 z = {0.f, 0.f, 0.f, 0.f};
    acc[nn] = z;
  }

#pragma unroll
  for (int kk = 0; kk < 8; ++kk) {
#pragma unroll
    for (int nn = 0; nn < 4; ++nn) {
      short8 bf = *(const short8*)&w1blk[(size_t)((kk * 4 + q) * 64 + nn * 16 + l16) * 8];
      acc[nn] = __builtin_amdgcn_mfma_f32_16x16x32_bf16(af[kk], bf, acc[nn], 0, 0, 0);
    }
  }

  // ---- epilogue (registers only) ----
  // C/D layout: col(n within tile) = l16, row(m within tile) = q*4 + reg.
  float p0 = 0.f, p1 = 0.f, p2 = 0.f, p3 = 0.f;
#pragma unroll
  for (int nn = 0; nn < 4; ++nn) {
    float bb = b1[nn * 16 + l16];
    float ww = W2[nn * 16 + l16];
    floatx4 a = acc[nn];
    p0 += fmaxf(a[0] + bb, 0.f) * ww;
    p1 += fmaxf(a[1] + bb, 0.f) * ww;
    p2 += fmaxf(a[2] + bb, 0.f) * ww;
    p3 += fmaxf(a[3] + bb, 0.f) * ww;
  }
  // butterfly over the 16 lanes of each quad-group (sum over n)
#pragma unroll
  for (int s = 1; s < 16; s <<= 1) {
    p0 += __shfl_xor(p0, s, 64);
    p1 += __shfl_xor(p1, s, 64);
    p2 += __shfl_xor(p2, s, 64);
    p3 += __shfl_xor(p3, s, 64);
  }
  if (l16 < 4) {
    float logit = (l16 == 0) ? p0 : (l16 == 1) ? p1 : (l16 == 2) ? p2 : p3;
    logit += b2[0];
    int eo = wavebase + q * 4 + l16;
    if (eo < num_edges) {
      float a1 = fminf(fmaxf(u1[eo], GS_EPS), 1.0f);
      float a2 = fminf(fmaxf(u2[eo], GS_EPS), 1.0f);
      float g1 = -__logf(-__logf(a1));
      float g2 = -__logf(-__logf(a2));
      float x = logit + g1 - g2;  // TEMP = 1.0
      out[eo] = 1.f / (1.f + __expf(-x));
    }
  }
}

extern "C" void kernel_launch(void* const* d_in, const int* in_sizes, int n_in,
                              void* d_out, int out_size, void* d_ws, size_t ws_size,
                              hipStream_t stream) {
  const float* node_embed = (const float*)d_in[0];
  const int* ei = (const int*)d_in[1];
  const float* u1 = (const float*)d_in[2];
  const float* u2 = (const float*)d_in[3];
  const float* W1 = (const float*)d_in[4];
  const float* b1 = (const float*)d_in[5];
  const float* W2 = (const float*)d_in[6];
  const float* b2 = (const float*)d_in[7];
  float* out = (float*)d_out;

  const int num_edges = in_sizes[2];        // u1 length
  const int num_nodes = in_sizes[0] / 128;  // embed_dim = 128

  unsigned short* node_bf16 = (unsigned short*)d_ws;
  const size_t node_tbl_bytes = (size_t)num_nodes * 128 * sizeof(unsigned short);
  unsigned short* w1blk = (unsigned short*)((char*)d_ws + ((node_tbl_bytes + 15) & ~(size_t)15));

  int n8 = (num_nodes * 128) / 8;
  conv_nodes_kernel<<<(n8 + 255) / 256, 256, 0, stream>>>(node_embed, node_bf16, n8);
  conv_w1_kernel<<<8, 256, 0, stream>>>(W1, w1blk);

  const int nblocks = (num_edges + 127) / 128;
  edge_mlp_kernel<<<nblocks, 512, 0, stream>>>(
      node_bf16, w1blk, ei, u1, u2, b1, W2, b2, out, num_edges);
}

// Round 4
// 116.084 us; speedup vs baseline: 1.2627x; 1.1689x over previous
//
#include <hip/hip_runtime.h>
#include <stdint.h>

typedef float  floatx4 __attribute__((ext_vector_type(4)));
typedef short  short8  __attribute__((ext_vector_type(8)));
typedef float  f4v     __attribute__((ext_vector_type(4)));
typedef unsigned int uint32;

#define GS_EPS 1e-10f

__device__ __forceinline__ unsigned short f2bf(float x) {
  uint32 u = __float_as_uint(x);
  u += 0x7FFFu + ((u >> 16) & 1u);
  return (unsigned short)(u >> 16);
}
__device__ __forceinline__ float bf2f(short v) {
  return __uint_as_float(((uint32)(unsigned short)v) << 16);
}

// ---- prep: W1 fp32 [256][64] -> W1cat bf16 blocked [chunk=k/8][n=0..128)][k%8]
// W1cat[k][n] = n<64 ? W1[k][n] : W1[128+k][n-64]   (k in [0,128))
__global__ void conv_w1cat_kernel(const float* __restrict__ W1,
                                  unsigned short* __restrict__ w1g) {
  int i = blockIdx.x * 256 + threadIdx.x;  // 0..2047 = chunk*128 + n
  int chunk = i >> 7;
  int n = i & 127;
  const float* src = (n < 64) ? (W1 + n) : (W1 + 128 * 64 + (n - 64));
  uint32 d[4];
#pragma unroll
  for (int j = 0; j < 4; ++j) {
    int k0 = chunk * 8 + 2 * j;
    unsigned short lo = f2bf(src[(size_t)k0 * 64]);
    unsigned short hi = f2bf(src[(size_t)(k0 + 1) * 64]);
    d[j] = (uint32)lo | ((uint32)hi << 16);
  }
#pragma unroll
  for (int j = 0; j < 4; ++j) *(uint32*)&w1g[(size_t)i * 8 + 2 * j] = d[j];
}

// ---- precompute P[node][0:64]=e@W1_top+b1, P[node][64:128]=e@W1_bot (bf16) ----
// A = W1cat fragment (m = hidden j), B = node rows (n = node). D col = node
// = l16, row = j = t*16 + q*4 + r  -> per-lane 4 consecutive j: packed 8B store,
// no transpose needed.
__global__ __launch_bounds__(512, 4) void pcompute_kernel(
    const float* __restrict__ E, const unsigned short* __restrict__ w1g,
    const float* __restrict__ b1, unsigned short* __restrict__ P,
    int num_nodes) {
  __shared__ __align__(16) unsigned short w1blk[16 * 128 * 8];  // 32 KB

  const int tid = threadIdx.x;
  const int wave = tid >> 6;
  const int lane = tid & 63;
  const int q = lane >> 4;
  const int l16 = lane & 15;

  // stage blocked W1cat: coalesced b128 reads, conflict-free b128 writes
#pragma unroll
  for (int it = 0; it < 4; ++it) {
    int idx = it * 512 + tid;
    short8 v = *(const short8*)(w1g + (size_t)idx * 8);
    *(short8*)&w1blk[(size_t)idx * 8] = v;
  }

  const int rowbase = blockIdx.x * 128 + wave * 16;
  int row = rowbase + l16;
  const bool ok = row < num_nodes;
  if (!ok) row = num_nodes - 1;

  // B-frags: E row (coalesced fp32 loads), convert to bf16 in-register
  short8 bfr[4];
#pragma unroll
  for (int kk = 0; kk < 4; ++kk) {
    const float* p = E + (size_t)row * 128 + kk * 32 + q * 8;
    f4v v0 = *(const f4v*)p;
    f4v v1 = *(const f4v*)(p + 4);
    short8 t;
    t[0] = (short)f2bf(v0[0]); t[1] = (short)f2bf(v0[1]);
    t[2] = (short)f2bf(v0[2]); t[3] = (short)f2bf(v0[3]);
    t[4] = (short)f2bf(v1[0]); t[5] = (short)f2bf(v1[1]);
    t[6] = (short)f2bf(v1[2]); t[7] = (short)f2bf(v1[3]);
    bfr[kk] = t;
  }
  __syncthreads();

  floatx4 acc[8];
#pragma unroll
  for (int t = 0; t < 8; ++t) {
    floatx4 z = {0.f, 0.f, 0.f, 0.f};
    acc[t] = z;
  }
#pragma unroll
  for (int kk = 0; kk < 4; ++kk) {
#pragma unroll
    for (int t = 0; t < 8; ++t) {
      short8 af = *(const short8*)&w1blk[(size_t)((kk * 4 + q) * 128 + t * 16 + l16) * 8];
      acc[t] = __builtin_amdgcn_mfma_f32_16x16x32_bf16(af, bfr[kk], acc[t], 0, 0, 0);
    }
  }

  // epilogue: fold b1 into top half (j<64 <=> t<4), pack 4 bf16, 8B store
#pragma unroll
  for (int t = 0; t < 8; ++t) {
    floatx4 a = acc[t];
    if (t < 4) {
      f4v bv = *(const f4v*)(b1 + t * 16 + q * 4);
      a[0] += bv[0]; a[1] += bv[1]; a[2] += bv[2]; a[3] += bv[3];
    }
    uint32 lo = (uint32)f2bf(a[0]) | ((uint32)f2bf(a[1]) << 16);
    uint32 hi = (uint32)f2bf(a[2]) | ((uint32)f2bf(a[3]) << 16);
    if (ok) {
      uint32* dst = (uint32*)(P + (size_t)(rowbase + l16) * 128 + t * 16 + q * 4);
      dst[0] = lo;
      dst[1] = hi;
    }
  }
}

// ---- edge kernel: MFMA-free gather + tiny dot + gumbel-sigmoid ----
// Block 256 = 4 waves; wave = 32 edges = 4 slots of 8 edges; 8 lanes/edge.
// Per edge: gather P[row][0:64] (128B) + P[col][64:128] (128B), both bf16.
__global__ __launch_bounds__(256, 8) void edge_kernel(
    const unsigned short* __restrict__ P,
    const int* __restrict__ ei,
    const float* __restrict__ u1, const float* __restrict__ u2,
    const float* __restrict__ W2, const float* __restrict__ b2,
    float* __restrict__ out, int num_edges) {
  const int tid = threadIdx.x;
  const int wave = tid >> 6;
  const int lane = tid & 63;
  const int g = lane >> 3;  // edge-within-slot
  const int h = lane & 7;   // lane-within-edge
  const int wbase = blockIdx.x * 128 + wave * 32;

  // per-lane W2 chunk (uniform across edges)
  f4v w0 = *(const f4v*)(W2 + h * 8);
  f4v w1v = *(const f4v*)(W2 + h * 8 + 4);
  const float bias2 = b2[0];

  // edge indices: lane l covers edge wbase + (l&31) (duplicated in upper 32)
  int el = wbase + (lane & 31);
  if (el > num_edges - 1) el = num_edges - 1;
  // int64-vs-int32 detection (per-wave uniform): int64 LE => odd words all 0
  unsigned long long oddmask = __ballot(ei[2 * el + 1] != 0);
  const bool idx64 = (oddmask == 0ULL);
  int eR, eC;
  if (idx64) {
    eR = ei[2 * el];
    eC = ei[2 * (num_edges + el)];
  } else {
    eR = ei[el];
    eC = ei[num_edges + el];
  }

  // issue all 8 gathers (4 slots x 2) back-to-back
  short8 ar[4], ac[4];
#pragma unroll
  for (int s = 0; s < 4; ++s) {
    int nr = __shfl(eR, s * 8 + g, 64);
    int nc = __shfl(eC, s * 8 + g, 64);
    ar[s] = *(const short8*)(P + (size_t)nr * 128 + h * 8);
    ac[s] = *(const short8*)(P + (size_t)nc * 128 + 64 + h * 8);
  }

#pragma unroll
  for (int s = 0; s < 4; ++s) {
    float acc = 0.f;
#pragma unroll
    for (int j = 0; j < 8; ++j) {
      float hv = fmaxf(bf2f(ar[s][j]) + bf2f(ac[s][j]), 0.f);  // b1 folded in P
      float ww = (j < 4) ? w0[j] : w1v[j - 4];
      acc = fmaf(hv, ww, acc);
    }
    acc += __shfl_xor(acc, 1, 64);
    acc += __shfl_xor(acc, 2, 64);
    acc += __shfl_xor(acc, 4, 64);
    if (h == 0) {
      int e = wbase + s * 8 + g;
      if (e < num_edges) {
        float a1 = fminf(fmaxf(u1[e], GS_EPS), 1.0f);
        float a2 = fminf(fmaxf(u2[e], GS_EPS), 1.0f);
        float g1 = -__logf(-__logf(a1));
        float g2 = -__logf(-__logf(a2));
        float x = acc + bias2 + g1 - g2;  // TEMP = 1.0
        out[e] = 1.f / (1.f + __expf(-x));
      }
    }
  }
}

extern "C" void kernel_launch(void* const* d_in, const int* in_sizes, int n_in,
                              void* d_out, int out_size, void* d_ws, size_t ws_size,
                              hipStream_t stream) {
  const float* node_embed = (const float*)d_in[0];
  const int* ei = (const int*)d_in[1];
  const float* u1 = (const float*)d_in[2];
  const float* u2 = (const float*)d_in[3];
  const float* W1 = (const float*)d_in[4];
  const float* b1 = (const float*)d_in[5];
  const float* W2 = (const float*)d_in[6];
  const float* b2 = (const float*)d_in[7];
  float* out = (float*)d_out;

  const int num_edges = in_sizes[2];        // u1 length
  const int num_nodes = in_sizes[0] / 128;  // embed_dim = 128

  // workspace: P table (bf16, num_nodes x 128) then blocked W1cat (32 KB)
  unsigned short* P = (unsigned short*)d_ws;
  const size_t p_bytes = (size_t)num_nodes * 128 * sizeof(unsigned short);
  unsigned short* w1g = (unsigned short*)((char*)d_ws + ((p_bytes + 255) & ~(size_t)255));

  conv_w1cat_kernel<<<8, 256, 0, stream>>>(W1, w1g);
  const int pblocks = (num_nodes + 127) / 128;
  pcompute_kernel<<<pblocks, 512, 0, stream>>>(node_embed, w1g, b1, P, num_nodes);
  const int eblocks = (num_edges + 127) / 128;
  edge_kernel<<<eblocks, 256, 0, stream>>>(P, ei, u1, u2, W2, b2, out, num_edges);
}